// Round 10
// baseline (177.389 us; speedup 1.0000x reference)
//
#include <hip/hip_runtime.h>

typedef __bf16 bf16;
typedef __attribute__((ext_vector_type(8))) __bf16 bf16x8;
typedef __attribute__((ext_vector_type(4))) __bf16 bf16x4;
typedef __attribute__((ext_vector_type(4))) float f32x4;
typedef __attribute__((ext_vector_type(2))) unsigned int u32x2;
typedef __attribute__((ext_vector_type(4))) int i32x4;

#define MFMA16(a, b, c) __builtin_amdgcn_mfma_f32_16x16x32_bf16((a), (b), (c), 0, 0, 0)

#define S_LEN 4096
#define NHEAD 12
#define EMB   768
#define NEGV  (-1e30f)

// async global->LDS, 16B per lane. LDS dest = wave-uniform base + lane*16 (linear);
// swizzled layouts are achieved by pre-swizzling the per-lane GLOBAL source addr.
__device__ __forceinline__ void gload16(const bf16* g, bf16* l) {
  __builtin_amdgcn_global_load_lds((const __attribute__((address_space(1))) void*)g,
                                   (__attribute__((address_space(3))) void*)l, 16, 0, 0);
}

// ---------------- kernel 0: f32 -> bf16 convert (optionally scaled) -------------
__global__ __launch_bounds__(256) void cvt_kernel(const float* __restrict__ x,
                                                  bf16* __restrict__ o, int n8, float scale) {
  int i = blockIdx.x * 256 + threadIdx.x;
  if (i >= n8) return;
  const float4* p = (const float4*)(x + (size_t)i * 8);
  float4 a = p[0], b = p[1];
  bf16x8 v;
  v[0] = (bf16)(a.x * scale); v[1] = (bf16)(a.y * scale);
  v[2] = (bf16)(a.z * scale); v[3] = (bf16)(a.w * scale);
  v[4] = (bf16)(b.x * scale); v[5] = (bf16)(b.y * scale);
  v[6] = (bf16)(b.z * scale); v[7] = (bf16)(b.w * scale);
  *(bf16x8*)(o + (size_t)i * 8) = v;
}

// y=0..2: weight matrices (Wq gets 1/sqrt(D) folded); y=3: amask -> additive bf16
__global__ __launch_bounds__(256) void cvt3_kernel(const float* __restrict__ w0,
                                                   const float* __restrict__ w1,
                                                   const float* __restrict__ w2,
                                                   bf16* __restrict__ o, int n8,
                                                   const float* __restrict__ amask,
                                                   bf16* __restrict__ am_out) {
  int which = blockIdx.y;
  if (which == 3) {
    int i = blockIdx.x * 256 + threadIdx.x;
    if (i < 2 * S_LEN) am_out[i] = (amask[i] != 0.f) ? (bf16)(-1e30f) : (bf16)0.f;
    return;
  }
  const float* src = (which == 0) ? w0 : (which == 1) ? w1 : w2;
  float scale = (which == 0) ? 0.125f : 1.0f;
  int i = blockIdx.x * 256 + threadIdx.x;
  if (i >= n8) return;
  const float4* p = (const float4*)(src + (size_t)i * 8);
  float4 a = p[0], b = p[1];
  bf16x8 v;
  v[0] = (bf16)(a.x * scale); v[1] = (bf16)(a.y * scale);
  v[2] = (bf16)(a.z * scale); v[3] = (bf16)(a.w * scale);
  v[4] = (bf16)(b.x * scale); v[5] = (bf16)(b.y * scale);
  v[6] = (bf16)(b.z * scale); v[7] = (bf16)(b.w * scale);
  *(bf16x8*)(o + ((size_t)which * n8 + i) * 8) = v;
}

// ---------------- kernel 1: fused QKV GEMM  out = X @ W^T + bias ----------------
// (unchanged from round 9: proven 2-phase double-buffered gload_lds + vec epilogue)
__global__ __launch_bounds__(256) void qkv_gemm(const bf16* __restrict__ Xb, const bf16* __restrict__ Wb,
                                                const float* __restrict__ bq, const float* __restrict__ bk,
                                                const float* __restrict__ bv,
                                                bf16* __restrict__ Qo, bf16* __restrict__ Ko,
                                                bf16* __restrict__ Vt) {
  __shared__ union SM {
    struct { bf16 a[2][128 * 64]; bf16 b2[2][128 * 64]; } st;
    bf16 c[128 * 130];
  } sm;
  const int tid = threadIdx.x;
  const int l = tid & 63, w = tid >> 6;
  const int ln = l & 15, g = l >> 4;
  const int wm = w >> 1, wn = w & 1;
  const int m0 = blockIdx.x * 128;
  const int n0 = blockIdx.y * 128;

  const f32x4 zero4 = {0.f, 0.f, 0.f, 0.f};
  f32x4 acc[4][4];
#pragma unroll
  for (int i = 0; i < 4; ++i)
#pragma unroll
    for (int j = 0; j < 4; ++j) acc[i][j] = zero4;

  int srow[4], sslot[4];
#pragma unroll
  for (int i = 0; i < 4; ++i) {
    const int G = w * 256 + i * 64 + l;
    srow[i] = G >> 3;
    sslot[i] = (G & 7) ^ (srow[i] & 7);
  }

  auto stage = [&](int sb, int kt) {
    const int k0 = kt * 64;
#pragma unroll
    for (int i = 0; i < 4; ++i) {
      gload16(Xb + (size_t)(m0 + srow[i]) * 768 + k0 + sslot[i] * 8, &sm.st.a[sb][(w * 256 + i * 64) * 8]);
      gload16(Wb + (size_t)(n0 + srow[i]) * 768 + k0 + sslot[i] * 8, &sm.st.b2[sb][(w * 256 + i * 64) * 8]);
    }
  };

  stage(0, 0);
  __syncthreads();

  int buf = 0;
  for (int kt = 0; kt < 12; ++kt, buf ^= 1) {
    if (kt < 11) stage(buf ^ 1, kt + 1);
#pragma unroll
    for (int kc = 0; kc < 2; ++kc) {
      bf16x8 af[4], bfr[4];
#pragma unroll
      for (int i = 0; i < 4; ++i) {
        int ra = wm * 64 + i * 16 + ln;
        af[i] = *(const bf16x8*)(&sm.st.a[buf][ra * 64 + ((kc * 4 + g) ^ (ra & 7)) * 8]);
        int rb = wn * 64 + i * 16 + ln;
        bfr[i] = *(const bf16x8*)(&sm.st.b2[buf][rb * 64 + ((kc * 4 + g) ^ (rb & 7)) * 8]);
      }
#pragma unroll
      for (int mi = 0; mi < 4; ++mi)
#pragma unroll
        for (int ni = 0; ni < 4; ++ni)
          acc[mi][ni] = MFMA16(af[mi], bfr[ni], acc[mi][ni]);
    }
    __syncthreads();
  }

  const int which = n0 / 768;
  const int h0 = (n0 % 768) >> 6;
  const int b = m0 >> 12;
  const int h = h0 + wn;
  const float bsc = (which == 0) ? 0.125f : 1.0f;
  const float* bias = (which == 0) ? bq : (which == 1) ? bk : bv;
  float bvv[4];
#pragma unroll
  for (int ni = 0; ni < 4; ++ni) bvv[ni] = bias[h * 64 + ni * 16 + ln] * bsc;

#pragma unroll
  for (int mi = 0; mi < 4; ++mi)
#pragma unroll
    for (int ni = 0; ni < 4; ++ni)
#pragma unroll
      for (int r = 0; r < 4; ++r) {
        int sl = wm * 64 + mi * 16 + g * 4 + r;
        sm.c[sl * 130 + wn * 64 + ni * 16 + ln] = (bf16)(acc[mi][ni][r] + bvv[ni]);
      }
  __syncthreads();

  if (which < 2) {
    bf16* dst = (which == 0) ? Qo : Ko;
#pragma unroll
    for (int it = 0; it < 8; ++it) {
      int gid = it * 256 + tid;
      int sl = gid >> 4, cg = gid & 15;
      int hh = h0 + (cg >> 3);
      bf16x8 v8 = *(const bf16x8*)(&sm.c[sl * 130 + cg * 8]);
      *(bf16x8*)(dst + ((size_t)(b * NHEAD + hh) * S_LEN + (m0 & 4095) + sl) * 64 + (cg & 7) * 8) = v8;
    }
  } else {
#pragma unroll
    for (int it = 0; it < 4; ++it) {
      int d = it * 32 + (tid >> 3);
      int scp = tid & 7;
      int hh = h0 + (d >> 6);
      bf16x8 o0, o1;
#pragma unroll
      for (int i2 = 0; i2 < 8; ++i2) o0[i2] = sm.c[(scp * 16 + i2) * 130 + d];
#pragma unroll
      for (int i2 = 0; i2 < 8; ++i2) o1[i2] = sm.c[(scp * 16 + 8 + i2) * 130 + d];
      bf16* dp = Vt + ((size_t)(b * NHEAD + hh) * 64 + (d & 63)) * S_LEN + (m0 & 4095) + scp * 16;
      *(bf16x8*)dp = o0;
      *(bf16x8*)(dp + 8) = o1;
    }
  }
}

// ---------------- kernel 2: banded flash attention ----------------
// QBLK=64, 4 waves x 16 q, 1536 blocks (6/CU of work, 5 resident at 32KB LDS ->
// ~5 independently-phased chains per SIMD vs 3 before). P^T exchange fully
// in-register via a 2-stage butterfly implementing the 3-cycle permutation
// (reg->lane5->lane4->reg): swap(reg,bit5) then swap(reg,bit4); each stage's
// shfl operand is selected by the SOURCE lane's own bit (the round-8 bug was
// selecting by destination bits). No Pt LDS; additive mask is bf16.
__global__ __launch_bounds__(256, 5) void attn_kernel(const bf16* __restrict__ Qb, const bf16* __restrict__ Kb,
                                                      const bf16* __restrict__ Vtb,
                                                      const bf16* __restrict__ Amb,
                                                      const unsigned char* __restrict__ imask,
                                                      float* __restrict__ out) {
  __shared__ bf16 Ks[2][64 * 64];    // [key][dim], swizzled content
  __shared__ bf16 Vs[2][64 * 64];    // [dim][key], swizzled content
  const int tid = threadIdx.x;
  const int l = tid & 63, w = tid >> 6;
  const int ln = l & 15, g = l >> 4;
  // XCD swizzle: 1536 blocks = 8 * 192, bijective
  const int orig = blockIdx.x;
  const int lb = (orig & 7) * 192 + (orig >> 3);
  const int qc = lb & 63, bh = lb >> 6;
  const int b = bh / NHEAD, h = bh % NHEAD;
  const int q0 = qc * 64;
  const int qg = q0 + w * 16 + ln;

  const size_t qoff = ((size_t)bh * S_LEN + qg) * 64;
  const bf16x8 qf0 = *(const bf16x8*)(Qb + qoff + g * 8);
  const bf16x8 qf1 = *(const bf16x8*)(Qb + qoff + 32 + g * 8);
  const bf16* Ab = Amb + b * S_LEN;

  const f32x4 zero4 = {0.f, 0.f, 0.f, 0.f};
  f32x4 acc[4];
#pragma unroll
  for (int i = 0; i < 4; ++i) acc[i] = zero4;
  float mrun = -1e38f, lrun = 0.f;

  const int t_lo = (q0 >= 256) ? 0 : ((256 - q0) >> 6);
  int t_hi = (S_LEN + 256 - q0) >> 6;
  if (t_hi > 9) t_hi = 9;

  auto stage = [&](int sb, int t) {
    const int tj0 = q0 - 256 + t * 64;
#pragma unroll
    for (int p = 0; p < 2; ++p) {
      const int G = p * 256 + w * 64 + l;      // granule 0..511
      const int row = G >> 3, dsl = G & 7;
      const int slot = dsl ^ (row & 7);
      gload16(Kb + ((size_t)bh * S_LEN + tj0 + row) * 64 + slot * 8, &Ks[sb][(p * 256 + w * 64) * 8]);
      gload16(Vtb + ((size_t)bh * 64 + row) * S_LEN + tj0 + slot * 8, &Vs[sb][(p * 256 + w * 64) * 8]);
    }
  };

  stage(0, t_lo);
  asm volatile("s_waitcnt vmcnt(0)" ::: "memory");
  __syncthreads();

  const bool b5 = (l & 32) != 0, b4 = (l & 16) != 0;

  int buf = 0;
  for (int t = t_lo; t < t_hi; ++t, buf ^= 1) {
    const int tj0 = q0 - 256 + t * 64;

    // additive mask (bf16), issued before the stage loads (older in vmcnt queue
    // -> softmax's am wait leaves the K/V prefetch in flight)
    bf16x4 am4[4];
#pragma unroll
    for (int mi = 0; mi < 4; ++mi) am4[mi] = *(const bf16x4*)(Ab + tj0 + mi * 16 + g * 4);

    if (t + 1 < t_hi) stage(buf ^ 1, t + 1);   // prefetch overlaps compute

    // QK^T (swapped): S^T[key][q]
    f32x4 sc[4];
#pragma unroll
    for (int i = 0; i < 4; ++i) sc[i] = zero4;
    __builtin_amdgcn_s_setprio(1);
#pragma unroll
    for (int kc = 0; kc < 2; ++kc) {
      bf16x8 qf = kc ? qf1 : qf0;
#pragma unroll
      for (int mi = 0; mi < 4; ++mi) {
        int r = mi * 16 + ln;
        bf16x8 kf = *(const bf16x8*)(&Ks[buf][r * 64 + ((kc * 4 + g) ^ (r & 7)) * 8]);
        sc[mi] = MFMA16(kf, qf, sc[mi]);
      }
    }
    __builtin_amdgcn_s_setprio(0);

    // mask + online softmax. Band check only on (uniform per-wave) partial tiles.
    float mt = -1e38f;
    const bool full = (t * 64 >= w * 16 + 15) && (t * 64 <= w * 16 + 449);
    if (full) {
#pragma unroll
      for (int mi = 0; mi < 4; ++mi)
#pragma unroll
        for (int r = 0; r < 4; ++r) {
          float v = sc[mi][r] + (float)am4[mi][r];
          sc[mi][r] = v;
          mt = fmaxf(mt, v);
        }
    } else {
#pragma unroll
      for (int mi = 0; mi < 4; ++mi)
#pragma unroll
        for (int r = 0; r < 4; ++r) {
          int j = tj0 + mi * 16 + g * 4 + r;
          bool valid = (j >= qg - 256) && (j <= qg + 256);
          float v = valid ? (sc[mi][r] + (float)am4[mi][r]) : NEGV;
          sc[mi][r] = v;
          mt = fmaxf(mt, v);
        }
    }
    mt = fmaxf(mt, __shfl_xor(mt, 16));
    mt = fmaxf(mt, __shfl_xor(mt, 32));
    // defer-max (T13): only rescale when the tile max moved by > 8
    if (!__all(mt <= mrun + 8.f)) {
      float mnew = fmaxf(mrun, mt);
      float corr = __expf(mrun - mnew);
      lrun *= corr;
#pragma unroll
      for (int i = 0; i < 4; ++i) acc[i] *= corr;
      mrun = mnew;
    }
    // exp + row-sum, packing P to bf16 pairs on the fly
    float psum = 0.f;
    u32x2 pku[4];
#pragma unroll
    for (int mi = 0; mi < 4; ++mi) {
      float p0 = __expf(sc[mi][0] - mrun), p1 = __expf(sc[mi][1] - mrun);
      float p2 = __expf(sc[mi][2] - mrun), p3 = __expf(sc[mi][3] - mrun);
      psum += (p0 + p1) + (p2 + p3);
      bf16x4 pk;
      pk[0] = (bf16)p0; pk[1] = (bf16)p1; pk[2] = (bf16)p2; pk[3] = (bf16)p3;
      pku[mi] = __builtin_bit_cast(u32x2, pk);
    }
    psum += __shfl_xor(psum, 16);
    psum += __shfl_xor(psum, 32);
    lrun += psum;

    // in-register P^T exchange: permutation (reg->lane5->lane4->reg) as two
    // reg<->lane-bit butterfly swaps. After both, reg index = dest chunk c.
    bf16x8 pf[2];
#pragma unroll
    for (int kc = 0; kc < 2; ++kc) {
      u32x2 R0 = pku[2 * kc], R1 = pku[2 * kc + 1];
      // swap(reg, lane-bit5): lane b5=0 sends R1, b5=1 sends R0
      u32x2 s, e;
      s = b5 ? R0 : R1;
      e[0] = (unsigned)__shfl_xor((int)s[0], 32);
      e[1] = (unsigned)__shfl_xor((int)s[1], 32);
      R0 = b5 ? e : R0;
      R1 = b5 ? R1 : e;
      // swap(reg, lane-bit4)
      s = b4 ? R0 : R1;
      e[0] = (unsigned)__shfl_xor((int)s[0], 16);
      e[1] = (unsigned)__shfl_xor((int)s[1], 16);
      R0 = b4 ? e : R0;
      R1 = b4 ? R1 : e;
      i32x4 q4 = {(int)R0[0], (int)R0[1], (int)R1[0], (int)R1[1]};
      pf[kc] = __builtin_bit_cast(bf16x8, q4);
    }

    // PV: O^T[d][q] += V^T[d][key] * P^T[key][q]
    __builtin_amdgcn_s_setprio(1);
#pragma unroll
    for (int ds2 = 0; ds2 < 4; ++ds2) {
#pragma unroll
      for (int kc = 0; kc < 2; ++kc) {
        int r = ds2 * 16 + ln;
        bf16x8 vf = *(const bf16x8*)(&Vs[buf][r * 64 + ((kc * 4 + g) ^ (r & 7)) * 8]);
        acc[ds2] = MFMA16(vf, pf[kc], acc[ds2]);
      }
    }
    __builtin_amdgcn_s_setprio(0);

    // drain prefetch, then barrier (shfl results are same-wave; no lgkm drain)
    asm volatile("s_waitcnt vmcnt(0)" ::: "memory");
    __builtin_amdgcn_s_barrier();
    __builtin_amdgcn_sched_barrier(0);
  }

  float rl = 1.0f / lrun;
  if (imask[b * S_LEN + qg] != 0) rl = 0.0f;
  float* ob = out + ((size_t)b * S_LEN + qg) * EMB + h * 64;
#pragma unroll
  for (int ds2 = 0; ds2 < 4; ++ds2) {
    float4 o;
    o.x = acc[ds2][0] * rl; o.y = acc[ds2][1] * rl;
    o.z = acc[ds2][2] * rl; o.w = acc[ds2][3] * rl;
    *(float4*)(ob + ds2 * 16 + g * 4) = o;
  }
}

extern "C" void kernel_launch(void* const* d_in, const int* in_sizes, int n_in,
                              void* d_out, int out_size, void* d_ws, size_t ws_size,
                              hipStream_t stream) {
  const float* X = (const float*)d_in[0];
  const float* amask = (const float*)d_in[1];
  const unsigned char* imask = (const unsigned char*)d_in[2];
  const float* Wq = (const float*)d_in[3];
  const float* bq = (const float*)d_in[4];
  const float* Wk = (const float*)d_in[5];
  const float* bk = (const float*)d_in[6];
  const float* Wv = (const float*)d_in[7];
  const float* bv = (const float*)d_in[8];
  float* out = (float*)d_out;

  bf16* Xb = (bf16*)d_ws;                  //  8192*768
  bf16* Wb = Xb + 6291456;                 //  3*768*768 (Wq*0.125, Wk, Wv)
  bf16* Qb = Wb + 3 * 589824;              //  (b,h,s,d)
  bf16* Kb = Qb + 6291456;                 //  (b,h,s,d)
  bf16* Vt = Kb + 6291456;                 //  (b,h,d,s)
  bf16* Amb = Vt + 6291456;                //  B*S additive mask (bf16)

  cvt_kernel<<<3072, 256, 0, stream>>>(X, Xb, 6291456 / 8, 1.0f);
  cvt3_kernel<<<dim3(288, 4), 256, 0, stream>>>(Wq, Wk, Wv, Wb, 589824 / 8, amask, Amb);
  qkv_gemm<<<dim3(64, 18), 256, 0, stream>>>(Xb, Wb, bq, bk, bv, Qb, Kb, Vt);
  attn_kernel<<<1536, 256, 0, stream>>>(Qb, Kb, Vt, Amb, imask, out);
}